// Round 8
// baseline (1356.403 us; speedup 1.0000x reference)
//
#include <hip/hip_runtime.h>
#include <math.h>

// Problem constants
#define NB   4096      // graphs
#define MM   64        // points per graph
#define KNN  3
#define FX   59
#define H    128
#define NN   (NB*MM)       // 262144 nodes
#define NE   (NN*KNN)      // 786432 edges
#define C1   256
#define EPSB 1e-5f
#define GRID 1024          // persistent blocks (4/CU at 29.7KB LDS -> co-resident)
#define GPB  4             // graphs per block

typedef __attribute__((ext_vector_type(8))) short short8;   // 8 bf16 (4 VGPRs)
typedef __attribute__((ext_vector_type(4))) float f32x4;

__device__ __forceinline__ float wave_red(float v) {
#pragma unroll
    for (int m = 32; m >= 1; m >>= 1) v += __shfl_xor(v, m, 64);
    return v;
}

__device__ __forceinline__ unsigned short f2bf(float f) {
    union { float f; unsigned u; } v; v.f = f;
    unsigned r = v.u + 0x7fffu + ((v.u >> 16) & 1u);   // round-to-nearest-even
    return (unsigned short)(r >> 16);
}

__device__ __forceinline__ float bf2f(unsigned short h) {
    union { unsigned u; float f; } v; v.u = ((unsigned)h) << 16; return v.f;
}

// Grid barrier: 1 atomic per block (1024 total - cold), agent scope acq/rel.
// Safe: all GRID blocks are co-resident by construction (LDS 29.7KB -> 5/CU
// capacity >= 4 needed; __launch_bounds__(256,4) caps VGPR at 128).
__device__ __forceinline__ void gridbar(unsigned int* ctr) {
    __syncthreads();
    if (threadIdx.x == 0) {
        __threadfence();
        __hip_atomic_fetch_add(ctr, 1u, __ATOMIC_ACQ_REL, __HIP_MEMORY_SCOPE_AGENT);
        while (__hip_atomic_load(ctr, __ATOMIC_ACQUIRE, __HIP_MEMORY_SCOPE_AGENT) < GRID)
            __builtin_amdgcn_s_sleep(8);
        __threadfence();
    }
    __syncthreads();
}

// ---------------------------------------------------------------------------
// pre-kernel: zero 8 barrier counters; W1t[n][k] = bf16(W1[k][n]), k-pad 64.
// ---------------------------------------------------------------------------
__global__ __launch_bounds__(256) void k_pre(
    const float* __restrict__ W1, unsigned short* __restrict__ W1t,
    unsigned int* __restrict__ bars)
{
    const int tid = threadIdx.x;
    if (tid < 8) bars[tid] = 0u;
    for (int t = tid; t < 128 * 64; t += 256) {
        int n = t >> 6, k = t & 63;
        W1t[t] = (k < 62) ? f2bf(W1[k * H + n]) : (unsigned short)0;
    }
}

// ---------------------------------------------------------------------------
// MEGA: all phases, R5-proven cores, plain partial stores, 8 grid barriers.
// ---------------------------------------------------------------------------
__global__ __launch_bounds__(256, 4) void k_mega(
    const float* __restrict__ x, const float* __restrict__ pos,
    const float* __restrict__ W1, const float* __restrict__ b1,
    const float* __restrict__ g1, const float* __restrict__ be1,
    const float* __restrict__ W2, const float* __restrict__ b2,
    const float* __restrict__ g2, const float* __restrict__ be2,
    const float* __restrict__ Wc1, const float* __restrict__ bc1,
    const float* __restrict__ gc1, const float* __restrict__ bec1,
    const float* __restrict__ Wc2, const float* __restrict__ bc2,
    const float* __restrict__ gc2, const float* __restrict__ bec2,
    const unsigned short* __restrict__ W1t,
    unsigned short* __restrict__ h1max,
    float* __restrict__ ps1s, float* __restrict__ ps1q,
    float* __restrict__ affine1,
    unsigned short* __restrict__ W2t, float* __restrict__ b2p,
    float* __restrict__ graphsum,
    float* __restrict__ ps2s, float* __restrict__ ps2q,
    float* __restrict__ affine2,
    float* __restrict__ c1raw,
    float* __restrict__ ps3s, float* __restrict__ ps3q,
    float* __restrict__ affine3,
    float* __restrict__ z, float* __restrict__ zs, float* __restrict__ zq,
    float* __restrict__ out,
    unsigned int* __restrict__ bars)
{
    __shared__ __align__(16) unsigned char smem[29696];
    float* pos_s          = (float*)(smem + 0);            // 768 B
    int*   nbr_s          = (int*)(smem + 768);            // 768 B
    float* b1_s           = (float*)(smem + 1536);         // 512 B
    float* w1p_s          = (float*)(smem + 2048);         // 1536 B
    unsigned short* a_s   = (unsigned short*)(smem + 3584);  // 64x72 bf16 (9216 B)
    unsigned short* u_s   = (unsigned short*)(smem + 12800); // 64x132 bf16 (16896 B)
    float* red_s          = (float*)(smem + 28672);        // small reduce scratch

    const int blk  = blockIdx.x, tid = threadIdx.x;
    const int lane = tid & 63;
    const int w    = tid >> 6;

    // ============================ PHASE A ================================
    // Per graph (4 per block): stage x,pos -> bf16 A; MFMA u; kNN; combine;
    // h1max; stats accumulated in registers across graphs.
    {
        // block-invariant LDS: b1, W1 pos-rows, A-tile K-pad (cols 62,63)
        if (tid < H) b1_s[tid] = b1[tid];
        for (int t = tid; t < 3 * H; t += 256) w1p_s[t] = W1[(FX + t / H) * H + (t % H)];
        if (tid < 128) a_s[(tid & 63) * 72 + 62 + (tid >> 6)] = 0;

        const int c_  = (w & 1) * 64 + lane;   // combine channel
        const int nh_ = w >> 1;                // combine node-half
        float sA = 0.f, qA = 0.f;              // stats accum across graphs

        const int m  = lane & 15;
        const int kg = lane >> 4;
        const int wcol = w * 32;

        for (int it = 0; it < GPB; ++it) {
            const int g = blk * GPB + it;
            if (it > 0) __syncthreads();       // prev combine done before restage
            // ---- stage x (3776 floats, 16/thread, run-tracked row/col) ----
            {
                const float* xg = x + (size_t)g * MM * FX;
                if (tid < 236) {
                    f32x4 v0 = *(const f32x4*)(xg + tid * 16 + 0);
                    f32x4 v1 = *(const f32x4*)(xg + tid * 16 + 4);
                    f32x4 v2 = *(const f32x4*)(xg + tid * 16 + 8);
                    f32x4 v3 = *(const f32x4*)(xg + tid * 16 + 12);
                    float vv[16] = { v0[0],v0[1],v0[2],v0[3], v1[0],v1[1],v1[2],v1[3],
                                     v2[0],v2[1],v2[2],v2[3], v3[0],v3[1],v3[2],v3[3] };
                    int idx = tid * 16;
                    int i = idx / FX, f = idx - i * FX;
#pragma unroll
                    for (int j = 0; j < 16; ++j) {
                        a_s[i * 72 + f] = f2bf(vv[j]);
                        if (++f == FX) { f = 0; ++i; }
                    }
                }
                const float* pg = pos + (size_t)g * MM * 3;
                if (tid < 48) {
                    f32x4 v = *(const f32x4*)(pg + tid * 4);
                    int idx = tid * 4;
                    int i = idx / 3, f = idx - i * 3;
#pragma unroll
                    for (int j = 0; j < 4; ++j) {
                        pos_s[idx + j] = v[j];
                        a_s[i * 72 + FX + f] = f2bf(v[j]);
                        if (++f == 3) { f = 0; ++i; }
                    }
                }
            }
            __syncthreads();

            // ---- kNN on wave 0 (strict <, matches top_k tie rule) ----
            if (tid < MM) {
                const float px = pos_s[tid * 3 + 0];
                const float py = pos_s[tid * 3 + 1];
                const float pz = pos_s[tid * 3 + 2];
                float d0 = 1e30f, d1 = 1e30f, d2 = 1e30f;
                int   i0 = 0, i1 = 0, i2 = 0;
                for (int j = 0; j < MM; ++j) {
                    if (j == tid) continue;
                    float dx = pos_s[j * 3 + 0] - px;
                    float dy = pos_s[j * 3 + 1] - py;
                    float dz = pos_s[j * 3 + 2] - pz;
                    float d = dx * dx + dy * dy + dz * dz;
                    if (d < d2) {
                        if (d < d1) {
                            d2 = d1; i2 = i1;
                            if (d < d0) { d1 = d0; i1 = i0; d0 = d; i0 = j; }
                            else        { d1 = d;  i1 = j; }
                        } else { d2 = d; i2 = j; }
                    }
                }
                nbr_s[tid * 3 + 0] = i0;
                nbr_s[tid * 3 + 1] = i1;
                nbr_s[tid * 3 + 2] = i2;
            }

            // ---- MFMA u = A @ W1t (wave owns 32 cols) ----
            short8 bfr[2][2];
#pragma unroll
            for (int ct = 0; ct < 2; ++ct)
#pragma unroll
                for (int kc = 0; kc < 2; ++kc)
                    bfr[ct][kc] = *(const short8*)(W1t + (wcol + ct * 16 + m) * 64 + kc * 32 + kg * 8);
            f32x4 acc[4][2];
#pragma unroll
            for (int rt = 0; rt < 4; ++rt)
#pragma unroll
                for (int ct = 0; ct < 2; ++ct) acc[rt][ct] = (f32x4){0.f, 0.f, 0.f, 0.f};
#pragma unroll
            for (int kc = 0; kc < 2; ++kc)
#pragma unroll
                for (int rt = 0; rt < 4; ++rt) {
                    short8 a = *(const short8*)(a_s + (rt * 16 + m) * 72 + kc * 32 + kg * 8);
#pragma unroll
                    for (int ct = 0; ct < 2; ++ct)
                        acc[rt][ct] = __builtin_amdgcn_mfma_f32_16x16x32_bf16(a, bfr[ct][kc], acc[rt][ct], 0, 0, 0);
                }
            // D layout: col=lane&15, row=(lane>>4)*4+reg [m89/m91]
#pragma unroll
            for (int rt = 0; rt < 4; ++rt)
#pragma unroll
                for (int ct = 0; ct < 2; ++ct)
#pragma unroll
                    for (int r = 0; r < 4; ++r)
                        u_s[(rt * 16 + kg * 4 + r) * 132 + wcol + ct * 16 + m] = f2bf(acc[rt][ct][r]);
            __syncthreads();

            // ---- combine (R5-proven): edge ReLU, max-agg, stats ----
            {
                const float b1v = b1_s[c_];
                const float wp0 = w1p_s[0 * H + c_], wp1 = w1p_s[1 * H + c_], wp2 = w1p_s[2 * H + c_];
                unsigned short* hout = h1max + (size_t)g * MM * H;
                for (int ii = 0; ii < 32; ++ii) {
                    int node = nh_ * 32 + ii;
                    int j0 = nbr_s[node * 3 + 0];
                    int j1 = nbr_s[node * 3 + 1];
                    int j2 = nbr_s[node * 3 + 2];
                    float wi = pos_s[node * 3 + 0] * wp0 + pos_s[node * 3 + 1] * wp1
                             + pos_s[node * 3 + 2] * wp2;
                    float base = b1v - wi;
                    float h0 = fmaxf(bf2f(u_s[j0 * 132 + c_]) + base, 0.f);
                    float h1 = fmaxf(bf2f(u_s[j1 * 132 + c_]) + base, 0.f);
                    float h2 = fmaxf(bf2f(u_s[j2 * 132 + c_]) + base, 0.f);
                    sA += h0 + h1 + h2;
                    qA += h0 * h0 + h1 * h1 + h2 * h2;
                    hout[node * H + c_] = f2bf(fmaxf(fmaxf(h0, h1), h2));
                }
            }
        }
        // block-level stats: nh pairs reduce via LDS, then 1 coalesced row
        __syncthreads();
        float* scrS = (float*)(smem + 0);      // pos/nbr dead
        float* scrQ = (float*)(smem + 1024);
        scrS[nh_ * 128 + c_] = sA;
        scrQ[nh_ * 128 + c_] = qA;
        __syncthreads();
        if (tid < H) {
            ps1s[(size_t)blk * H + tid] = scrS[tid] + scrS[128 + tid];
            ps1q[(size_t)blk * H + tid] = scrQ[tid] + scrQ[128 + tid];
        }
    }
    gridbar(bars + 0);

    // ============================ PHASE B ================================
    // blocks 0..127: affine1[c] from ps1 columns
    if (blk < H) {
        float s = 0.f, q = 0.f;
        for (int p = tid; p < GRID; p += 256) {
            s += ps1s[(size_t)p * H + blk];
            q += ps1q[(size_t)p * H + blk];
        }
        s = wave_red(s); q = wave_red(q);
        if (lane == 0) { red_s[w] = s; red_s[4 + w] = q; }
        __syncthreads();
        if (tid == 0) {
            float S = red_s[0] + red_s[1] + red_s[2] + red_s[3];
            float Q = red_s[4] + red_s[5] + red_s[6] + red_s[7];
            float mu  = S * (1.f / (float)NE);
            float var = Q * (1.f / (float)NE) - mu * mu;
            float a   = g1[blk] * rsqrtf(var + EPSB);
            affine1[blk]     = a;
            affine1[H + blk] = be1[blk] - mu * a;
        }
    }
    gridbar(bars + 1);

    // ============================ PHASE C ================================
    // blocks 0..127: W2t[n][k] = bf16(a1[k]*W2[k][n]); b2p[n]
    if (blk < H) {
        float contrib = 0.f;
        if (tid < H) {
            float wv = W2[tid * H + blk];
            W2t[blk * H + tid] = f2bf(affine1[tid] * wv);
            contrib = affine1[H + tid] * wv;
        }
        float r = wave_red(contrib);
        if (lane == 0) red_s[w] = r;
        __syncthreads();
        if (tid == 0) b2p[blk] = b2[blk] + red_s[0] + red_s[1] + red_s[2] + red_s[3];
    }
    gridbar(bars + 2);

    // ============================ PHASE D ================================
    // mfma2 (R3/R5-proven LDS-staged core), 4 graphs/block, bfr hoisted
    {
        unsigned short* aD = (unsigned short*)(smem + 0);   // 64x136 bf16 (17408 B)
        float* scrS2 = (float*)(smem + 20480);
        float* scrQ2 = (float*)(smem + 21504);
        const int m = lane & 15, kg = lane >> 4, wcol = w * 32;
        short8 bfr[2][4];
#pragma unroll
        for (int ct = 0; ct < 2; ++ct)
#pragma unroll
            for (int kc = 0; kc < 4; ++kc)
                bfr[ct][kc] = *(const short8*)(W2t + (wcol + ct * 16 + m) * H + kc * 32 + kg * 8);
        float bv0 = b2p[wcol + m], bv1 = b2p[wcol + 16 + m];
        float sacc[2] = {0.f, 0.f}, qacc[2] = {0.f, 0.f};

        for (int it = 0; it < GPB; ++it) {
            const int g = blk * GPB + it;
            __syncthreads();                   // prev MFMA reads done
            const unsigned short* hg = h1max + (size_t)g * MM * H;
            for (int t = tid; t < MM * H / 8; t += 256) {
                int row = t >> 4, col8 = (t & 15) * 8;
                *(short8*)(aD + row * 136 + col8) = *(const short8*)(hg + row * H + col8);
            }
            __syncthreads();

            f32x4 acc[4][2];
#pragma unroll
            for (int rt = 0; rt < 4; ++rt)
#pragma unroll
                for (int ct = 0; ct < 2; ++ct) acc[rt][ct] = (f32x4){0.f, 0.f, 0.f, 0.f};
#pragma unroll
            for (int kc = 0; kc < 4; ++kc)
#pragma unroll
                for (int rt = 0; rt < 4; ++rt) {
                    short8 a = *(const short8*)(aD + (rt * 16 + m) * 136 + kc * 32 + kg * 8);
#pragma unroll
                    for (int ct = 0; ct < 2; ++ct)
                        acc[rt][ct] = __builtin_amdgcn_mfma_f32_16x16x32_bf16(a, bfr[ct][kc], acc[rt][ct], 0, 0, 0);
                }
#pragma unroll
            for (int ct = 0; ct < 2; ++ct) {
                float bv = ct ? bv1 : bv0;
                float s = 0.f, q = 0.f;
#pragma unroll
                for (int rt = 0; rt < 4; ++rt)
#pragma unroll
                    for (int r = 0; r < 4; ++r) {
                        float v = fmaxf(acc[rt][ct][r] + bv, 0.f);
                        s += v; q += v * v;
                    }
                s += __shfl_xor(s, 16, 64); q += __shfl_xor(q, 16, 64);
                s += __shfl_xor(s, 32, 64); q += __shfl_xor(q, 32, 64);
                if (lane < 16) {
                    int col = wcol + ct * 16 + lane;
                    graphsum[(size_t)g * H + col] = s;
                    sacc[ct] += s; qacc[ct] += q;
                }
            }
        }
#pragma unroll
        for (int ct = 0; ct < 2; ++ct)
            if (lane < 16) {
                scrS2[wcol + ct * 16 + lane] = sacc[ct];
                scrQ2[wcol + ct * 16 + lane] = qacc[ct];
            }
        __syncthreads();
        if (tid < H) {
            ps2s[(size_t)blk * H + tid] = scrS2[tid];
            ps2q[(size_t)blk * H + tid] = scrQ2[tid];
        }
    }
    gridbar(bars + 3);

    // ============================ PHASE E ================================
    if (blk < H) {
        float s = 0.f, q = 0.f;
        for (int p = tid; p < GRID; p += 256) {
            s += ps2s[(size_t)p * H + blk];
            q += ps2q[(size_t)p * H + blk];
        }
        s = wave_red(s); q = wave_red(q);
        if (lane == 0) { red_s[w] = s; red_s[4 + w] = q; }
        __syncthreads();
        if (tid == 0) {
            float S = red_s[0] + red_s[1] + red_s[2] + red_s[3];
            float Q = red_s[4] + red_s[5] + red_s[6] + red_s[7];
            float mu  = S * (1.f / (float)NN);
            float var = Q * (1.f / (float)NN) - mu * mu;
            float a   = g2[blk] * rsqrtf(var + EPSB);
            affine2[blk]     = a;
            affine2[H + blk] = be2[blk] - mu * a;
        }
    }
    gridbar(bars + 4);

    // ============================ PHASE F ================================
    // blocks 0..255: cls1 (16 graphs x 256 channels), R5 core
    if (blk < 256) {
        float* pooled_s = (float*)(smem + 0);  // 8 KB
        const int g0 = blk * 16;
        for (int t = tid; t < 16 * H; t += 256) {
            int f = t & 127;
            pooled_s[t] = affine2[f] * (graphsum[(size_t)g0 * H + t] * (1.f / 64.f)) + affine2[H + f];
        }
        __syncthreads();
        const int c = tid;
        float acc[16];
        const float bias = bc1[c];
#pragma unroll
        for (int gi = 0; gi < 16; ++gi) acc[gi] = bias;
        for (int f = 0; f < H; ++f) {
            float wv = Wc1[f * C1 + c];
#pragma unroll
            for (int gi = 0; gi < 16; ++gi) acc[gi] += pooled_s[gi * H + f] * wv;
        }
        float s = 0.f, q = 0.f;
#pragma unroll
        for (int gi = 0; gi < 16; ++gi) {
            float h = fmaxf(acc[gi], 0.f);
            c1raw[(size_t)(g0 + gi) * C1 + c] = h;
            s += h; q += h * h;
        }
        ps3s[(size_t)blk * C1 + c] = s;
        ps3q[(size_t)blk * C1 + c] = q;
    }
    gridbar(bars + 5);

    // ============================ PHASE G ================================
    // blocks 0..255: affine3[c]
    if (blk < C1) {
        float s = ps3s[(size_t)tid * C1 + blk];
        float q = ps3q[(size_t)tid * C1 + blk];
        s = wave_red(s); q = wave_red(q);
        if (lane == 0) { red_s[w] = s; red_s[4 + w] = q; }
        __syncthreads();
        if (tid == 0) {
            float S = red_s[0] + red_s[1] + red_s[2] + red_s[3];
            float Q = red_s[4] + red_s[5] + red_s[6] + red_s[7];
            float mu  = S * (1.f / (float)NB);
            float var = Q * (1.f / (float)NB) - mu * mu;
            float a   = gc1[blk] * rsqrtf(var + EPSB);
            affine3[blk]      = a;
            affine3[C1 + blk] = bec1[blk] - mu * a;
        }
    }
    gridbar(bars + 6);

    // ============================ PHASE H ================================
    // blocks 0..15: z per graph + block partial stats
    if (blk < 16) {
        float* a_sC = (float*)(smem + 0);
        float* c_sC = (float*)(smem + 1024);
        float* w_sC = (float*)(smem + 2048);
        a_sC[tid] = affine3[tid];
        c_sC[tid] = affine3[C1 + tid];
        w_sC[tid] = Wc2[tid];
        __syncthreads();
        const int g = blk * 256 + tid;
        float acc = bc2[0];
        for (int f = 0; f < C1; f += 4) {
            float4 cv = *(const float4*)&c1raw[(size_t)g * C1 + f];
            acc += (a_sC[f + 0] * cv.x + c_sC[f + 0]) * w_sC[f + 0];
            acc += (a_sC[f + 1] * cv.y + c_sC[f + 1]) * w_sC[f + 1];
            acc += (a_sC[f + 2] * cv.z + c_sC[f + 2]) * w_sC[f + 2];
            acc += (a_sC[f + 3] * cv.w + c_sC[f + 3]) * w_sC[f + 3];
        }
        float zz = fmaxf(acc, 0.f);
        z[g] = zz;
        float s = wave_red(zz);
        float q = wave_red(zz * zz);
        if (lane == 0) { red_s[w] = s; red_s[4 + w] = q; }
        __syncthreads();
        if (tid == 0) {
            zs[blk] = red_s[0] + red_s[1] + red_s[2] + red_s[3];
            zq[blk] = red_s[4] + red_s[5] + red_s[6] + red_s[7];
        }
    }
    gridbar(bars + 7);

    // ============================ PHASE I ================================
    if (blk == 0) {
        if (tid == 0) {
            float S = 0.f, Q = 0.f;
            for (int p = 0; p < 16; ++p) { S += zs[p]; Q += zq[p]; }
            float mu  = S * (1.f / (float)NB);
            float var = Q * (1.f / (float)NB) - mu * mu;
            float a   = gc2[0] * rsqrtf(var + EPSB);
            red_s[0] = a;
            red_s[1] = bec2[0] - mu * a;
        }
        __syncthreads();
        float a = red_s[0], cb = red_s[1];
        for (int g = tid; g < NB; g += 256) {
            float v = a * z[g] + cb;
            out[g] = 1.f / (1.f + expf(-v));
        }
    }
}

extern "C" void kernel_launch(void* const* d_in, const int* in_sizes, int n_in,
                              void* d_out, int out_size, void* d_ws, size_t ws_size,
                              hipStream_t stream)
{
    const float* x    = (const float*)d_in[0];
    const float* pos  = (const float*)d_in[1];
    // d_in[2] = batch (int32) — graphs are contiguous 64-node chunks; unused
    const float* W1   = (const float*)d_in[3];
    const float* b1   = (const float*)d_in[4];
    const float* g1   = (const float*)d_in[5];
    const float* be1  = (const float*)d_in[6];
    const float* W2   = (const float*)d_in[7];
    const float* b2   = (const float*)d_in[8];
    const float* g2   = (const float*)d_in[9];
    const float* be2  = (const float*)d_in[10];
    const float* Wc1  = (const float*)d_in[11];
    const float* bc1  = (const float*)d_in[12];
    const float* gc1  = (const float*)d_in[13];
    const float* bec1 = (const float*)d_in[14];
    const float* Wc2  = (const float*)d_in[15];
    const float* bc2  = (const float*)d_in[16];
    const float* gc2  = (const float*)d_in[17];
    const float* bec2 = (const float*)d_in[18];
    float* out = (float*)d_out;

    float* ws = (float*)d_ws;
    size_t off = 0;
    auto alloc = [&](size_t n) { float* p = ws + off; off += n; return p; };
    unsigned short* h1max = (unsigned short*)alloc((size_t)NN * H / 2);  // bf16, 67 MB
    unsigned short* W1t   = (unsigned short*)alloc(128 * 64 / 2);
    unsigned short* W2t   = (unsigned short*)alloc(128 * 128 / 2);
    float* b2p      = alloc(H);
    float* ps1s     = alloc((size_t)GRID * H);
    float* ps1q     = alloc((size_t)GRID * H);
    float* affine1  = alloc(2 * H);
    float* graphsum = alloc((size_t)NB * H);
    float* ps2s     = alloc((size_t)GRID * H);
    float* ps2q     = alloc((size_t)GRID * H);
    float* affine2  = alloc(2 * H);
    float* c1raw    = alloc((size_t)NB * C1);
    float* ps3s     = alloc((size_t)256 * C1);
    float* ps3q     = alloc((size_t)256 * C1);
    float* affine3  = alloc(2 * C1);
    float* zbuf     = alloc(NB);
    float* zs       = alloc(16);
    float* zq       = alloc(16);
    unsigned int* bars = (unsigned int*)alloc(8);

    k_pre<<<dim3(1), dim3(256), 0, stream>>>(W1, W1t, bars);
    k_mega<<<dim3(GRID), dim3(256), 0, stream>>>(
        x, pos, W1, b1, g1, be1, W2, b2, g2, be2,
        Wc1, bc1, gc1, bec1, Wc2, bc2, gc2, bec2,
        W1t, h1max, ps1s, ps1q, affine1, W2t, b2p, graphsum,
        ps2s, ps2q, affine2, c1raw, ps3s, ps3q, affine3,
        zbuf, zs, zq, out, bars);
}